// Round 1
// baseline (974.930 us; speedup 1.0000x reference)
//
#include <hip/hip_runtime.h>
#include <hip/hip_bf16.h>
#include <stdint.h>

// B=128, S=256, U=1024, E=256, V=32000
// out = [logits (128x32000) f32 ; h (128x1024) f32]

typedef __attribute__((ext_vector_type(8))) short bf16x8;
typedef __attribute__((ext_vector_type(4))) float f32x4;

static __device__ __forceinline__ uint16_t f2bf(float f) {
    __hip_bfloat16 h = __float2bfloat16(f);
    return *reinterpret_cast<uint16_t*>(&h);
}
static __device__ __forceinline__ float sigm(float x) { return 1.0f / (1.0f + expf(-x)); }

// ---------------- f32 -> bf16 vectorized convert (8 elems/thread) ----------------
__global__ void cvt_bf16(const float* __restrict__ src, uint16_t* __restrict__ dst, int n8) {
    int i = blockIdx.x * blockDim.x + threadIdx.x;
    int stride = gridDim.x * blockDim.x;
    for (; i < n8; i += stride) {
        const float4* s = (const float4*)(src + (size_t)i * 8);
        float4 a = s[0], b = s[1];
        uint16_t t[8] = {f2bf(a.x), f2bf(a.y), f2bf(a.z), f2bf(a.w),
                         f2bf(b.x), f2bf(b.y), f2bf(b.z), f2bf(b.w)};
        *(uint4*)(dst + (size_t)i * 8) = *(uint4*)t;
    }
}

// ---------------- transpose + cvt: src f32 [Ksrc][Nsrc] -> dst bf16 [Nsrc][Ksrc] ----
// tile 32(k) x 64(n), 256 threads
__global__ void transpose_cvt(const float* __restrict__ src, uint16_t* __restrict__ dst,
                              int Ksrc, int Nsrc) {
    __shared__ float ls[32 * 65];
    int ktiles = Ksrc >> 5;
    int kt = blockIdx.x % ktiles, nt = blockIdx.x / ktiles;
    int k0 = kt * 32, n0 = nt * 64;
    int t = threadIdx.x;
    {
        int r = t >> 3, c = (t & 7) * 8;
        const float4* s = (const float4*)(src + (size_t)(k0 + r) * Nsrc + n0 + c);
        float4 v0 = s[0], v1 = s[1];
        float* d = &ls[r * 65 + c];
        d[0] = v0.x; d[1] = v0.y; d[2] = v0.z; d[3] = v0.w;
        d[4] = v1.x; d[5] = v1.y; d[6] = v1.z; d[7] = v1.w;
    }
    __syncthreads();
    {
        int n = t >> 2, kk = (t & 3) * 8;
        uint16_t r[8];
        #pragma unroll
        for (int i = 0; i < 8; ++i) r[i] = f2bf(ls[(kk + i) * 65 + n]);
        *(uint4*)(dst + (size_t)(n0 + n) * Ksrc + k0 + kk) = *(uint4*)r;
    }
}

// ---------------- skinny GEMM: C[128][N] = A[128][K](bf16) @ Bt[N][K](bf16)^T + bias --
// BN=16 per block, full M=128, wave-split-K (4 waves: 2 M-halves x 2 k-windows),
// chunk KC=64, register prefetch double-buffer.
__global__ __launch_bounds__(256) void gemm_skinny(const uint16_t* __restrict__ A,
                                                   const uint16_t* __restrict__ Bt,
                                                   const float* __restrict__ bias,
                                                   float* __restrict__ C, int ldc, int K) {
    __shared__ uint16_t As[128 * 72];  // 64 data + 8 pad per row
    __shared__ uint16_t Bs[16 * 72];
    int n0 = blockIdx.x * 16;
    int t = threadIdx.x;
    int w = t >> 6, l = t & 63, lm = l & 15, g = l >> 4;
    int kw = (w & 1) * 32;        // k-window (ushort offset within chunk)
    int mb = (w >> 1) * 64;       // M-half base row
    f32x4 acc[4];
    const f32x4 z4 = {0.f, 0.f, 0.f, 0.f};
    #pragma unroll
    for (int i = 0; i < 4; ++i) acc[i] = z4;
    int chunks = K >> 6;
    int row = t >> 1, half = t & 1;
    int bn = t >> 4, boff = (t & 15) * 4;
    uint4 ra[4]; uint2 rb;
    {
        const uint4* sa = (const uint4*)(A + (size_t)row * K + half * 32);
        ra[0] = sa[0]; ra[1] = sa[1]; ra[2] = sa[2]; ra[3] = sa[3];
        rb = *(const uint2*)(Bt + (size_t)(n0 + bn) * K + boff);
    }
    for (int c = 0; c < chunks; ++c) {
        __syncthreads();
        {
            uint4* da = (uint4*)&As[row * 72 + half * 32];
            da[0] = ra[0]; da[1] = ra[1]; da[2] = ra[2]; da[3] = ra[3];
            *(uint2*)&Bs[bn * 72 + boff] = rb;
        }
        __syncthreads();
        if (c + 1 < chunks) {
            const uint4* na = (const uint4*)(A + (size_t)row * K + (c + 1) * 64 + half * 32);
            ra[0] = na[0]; ra[1] = na[1]; ra[2] = na[2]; ra[3] = na[3];
            rb = *(const uint2*)(Bt + (size_t)(n0 + bn) * K + (c + 1) * 64 + boff);
        }
        bf16x8 bfr = *(const bf16x8*)&Bs[lm * 72 + kw + g * 8];
        #pragma unroll
        for (int mi = 0; mi < 4; ++mi) {
            bf16x8 af = *(const bf16x8*)&As[(mb + mi * 16 + lm) * 72 + kw + g * 8];
            acc[mi] = __builtin_amdgcn_mfma_f32_16x16x32_bf16(af, bfr, acc[mi], 0, 0, 0);
        }
    }
    // reduce the two k-windows per M-half via LDS
    __syncthreads();
    float* red = (float*)As;  // 2 * 128 * 16 f32 = 16 KB
    #pragma unroll
    for (int mi = 0; mi < 4; ++mi)
        #pragma unroll
        for (int r = 0; r < 4; ++r)
            red[((w & 1) * 128 + mb + mi * 16 + g * 4 + r) * 16 + lm] = acc[mi][r];
    __syncthreads();
    #pragma unroll
    for (int i = 0; i < 8; ++i) {
        int o = t * 8 + i;
        int m = o >> 4, n = o & 15;
        float s = red[m * 16 + n] + red[2048 + m * 16 + n] + bias[n0 + n];
        C[(size_t)m * ldc + n0 + n] = s;
    }
}

// ---------------- big GEMM (keys) + fused score epilogue -------------------------
// A = enc f32 [32768][1024] (cvt on the fly), Bt = W2t bf16 [1024][1024]
// score[m] += sum_n tanh(q[b][n] + W2_b[n] + keys[m][n]) * V_w[n]
__global__ __launch_bounds__(256) void gemm_big(const float* __restrict__ A,
                                                const uint16_t* __restrict__ Bt,
                                                const float* __restrict__ q,
                                                const float* __restrict__ w2b,
                                                const float* __restrict__ vw,
                                                float* __restrict__ score) {
    __shared__ uint16_t As[128 * 40];  // 32 data + 8 pad per row (80B rows)
    __shared__ uint16_t Bs[128 * 40];
    int bid = blockIdx.x;
    int nidx = bid & 7, midx = bid >> 3;   // n-inner: 8 consecutive blocks share A-tile
    int m0 = midx * 128, n0 = nidx * 128;
    const int K = 1024;
    int t = threadIdx.x;
    int w = t >> 6, l = t & 63, lm = l & 15, g = l >> 4;
    int wr = w >> 1, wc = w & 1;
    f32x4 acc[4][4];
    const f32x4 z4 = {0.f, 0.f, 0.f, 0.f};
    #pragma unroll
    for (int mi = 0; mi < 4; ++mi)
        #pragma unroll
        for (int ni = 0; ni < 4; ++ni) acc[mi][ni] = z4;
    int row = t >> 1, half = t & 1;
    for (int kt = 0; kt < 32; ++kt) {
        __syncthreads();
        {
            // A: 16 f32 -> 16 bf16 per thread
            const float4* sa = (const float4*)(A + (size_t)(m0 + row) * K + kt * 32 + half * 16);
            float4 va = sa[0], vb = sa[1], vc = sa[2], vd = sa[3];
            uint16_t tmp[16] = {f2bf(va.x), f2bf(va.y), f2bf(va.z), f2bf(va.w),
                                f2bf(vb.x), f2bf(vb.y), f2bf(vb.z), f2bf(vb.w),
                                f2bf(vc.x), f2bf(vc.y), f2bf(vc.z), f2bf(vc.w),
                                f2bf(vd.x), f2bf(vd.y), f2bf(vd.z), f2bf(vd.w)};
            uint4* da = (uint4*)&As[row * 40 + half * 16];
            da[0] = *(uint4*)&tmp[0]; da[1] = *(uint4*)&tmp[8];
            // B: already bf16
            const uint4* sb = (const uint4*)(Bt + (size_t)(n0 + row) * K + kt * 32 + half * 16);
            uint4* db = (uint4*)&Bs[row * 40 + half * 16];
            db[0] = sb[0]; db[1] = sb[1];
        }
        __syncthreads();
        bf16x8 af[4], bf[4];
        #pragma unroll
        for (int mi = 0; mi < 4; ++mi) af[mi] = *(const bf16x8*)&As[(wr * 64 + mi * 16 + lm) * 40 + g * 8];
        #pragma unroll
        for (int ni = 0; ni < 4; ++ni) bf[ni] = *(const bf16x8*)&Bs[(wc * 64 + ni * 16 + lm) * 40 + g * 8];
        #pragma unroll
        for (int mi = 0; mi < 4; ++mi)
            #pragma unroll
            for (int ni = 0; ni < 4; ++ni)
                acc[mi][ni] = __builtin_amdgcn_mfma_f32_16x16x32_bf16(af[mi], bf[ni], acc[mi][ni], 0, 0, 0);
    }
    // fused score epilogue: block lies entirely within one batch b (128-row blocks, S=256)
    int b = m0 >> 8;
    float qv[4], vv[4];
    #pragma unroll
    for (int ni = 0; ni < 4; ++ni) {
        int col = n0 + wc * 64 + ni * 16 + lm;
        qv[ni] = q[b * 1024 + col] + w2b[col];
        vv[ni] = vw[col];
    }
    #pragma unroll
    for (int mi = 0; mi < 4; ++mi) {
        #pragma unroll
        for (int r = 0; r < 4; ++r) {
            float p = tanhf(qv[0] + acc[mi][0][r]) * vv[0]
                    + tanhf(qv[1] + acc[mi][1][r]) * vv[1]
                    + tanhf(qv[2] + acc[mi][2][r]) * vv[2]
                    + tanhf(qv[3] + acc[mi][3][r]) * vv[3];
            p += __shfl_xor(p, 1); p += __shfl_xor(p, 2);
            p += __shfl_xor(p, 4); p += __shfl_xor(p, 8);
            if (lm == 0) atomicAdd(&score[m0 + wr * 64 + mi * 16 + g * 4 + r], p);
        }
    }
}

// ---------------- softmax over S=256 per row b (in place) ------------------------
__global__ void softmax_S(float* __restrict__ sc) {
    int b = blockIdx.x, t = threadIdx.x;
    float v = sc[b * 256 + t];
    float m = v;
    for (int mask = 32; mask >= 1; mask >>= 1) m = fmaxf(m, __shfl_xor(m, mask));
    __shared__ float sm[4], ssum[4];
    int w = t >> 6;
    if ((t & 63) == 0) sm[w] = m;
    __syncthreads();
    m = fmaxf(fmaxf(sm[0], sm[1]), fmaxf(sm[2], sm[3]));
    float e = expf(v - m);
    float s = e;
    for (int mask = 32; mask >= 1; mask >>= 1) s += __shfl_xor(s, mask);
    if ((t & 63) == 0) ssum[w] = s;
    __syncthreads();
    s = ssum[0] + ssum[1] + ssum[2] + ssum[3];
    sc[b * 256 + t] = e / s;
}

// ---------------- embedding gather -> inp1_16[:,1024:1280] -----------------------
__global__ void embed_k(const int* __restrict__ x, const float* __restrict__ emb,
                        uint16_t* __restrict__ inp1_16) {
    int b = blockIdx.x, e = threadIdx.x;
    float v = emb[(size_t)x[b] * 256 + e];
    inp1_16[b * 1280 + 1024 + e] = f2bf(v);
}

// ---------------- context = sum_s attn[b][s] * enc[b][s][:] ----------------------
__global__ void context_k(const float* __restrict__ attn, const float* __restrict__ enc,
                          uint16_t* __restrict__ inp1_16, uint16_t* __restrict__ inpL16) {
    int b = blockIdx.x >> 2, uc = blockIdx.x & 3;
    int t = threadIdx.x;
    int u = uc * 256 + t;
    __shared__ float sa[256];
    sa[t] = attn[b * 256 + t];
    __syncthreads();
    float acc = 0.f;
    const float* e = enc + (size_t)b * 256 * 1024 + u;
    #pragma unroll 8
    for (int s = 0; s < 256; ++s) acc += sa[s] * e[(size_t)s * 1024];
    uint16_t bv = f2bf(acc);
    inp1_16[b * 1280 + u] = bv;
    inpL16[b * 2048 + u] = bv;
}

// ---------------- LSTM gates: z[128][4096] -> h -----------------------------------
__global__ void gates_k(const float* __restrict__ z, uint16_t* __restrict__ inpL16,
                        float* __restrict__ hout, uint16_t* __restrict__ h16) {
    int idx = blockIdx.x * 256 + threadIdx.x;  // 131072
    int b = idx >> 10, j = idx & 1023;
    const float* zb = z + (size_t)b * 4096;
    float i = zb[j], g = zb[2048 + j], o = zb[3072 + j];
    float c = sigm(i) * tanhf(g);
    float h = sigm(o) * tanhf(c);
    inpL16[b * 2048 + 1024 + j] = f2bf(h);
    if (hout) {
        hout[(size_t)b * 1024 + j] = h;
        h16[b * 1024 + j] = f2bf(h);
    }
}

extern "C" void kernel_launch(void* const* d_in, const int* in_sizes, int n_in,
                              void* d_out, int out_size, void* d_ws, size_t ws_size,
                              hipStream_t stream) {
    const int*   x      = (const int*)d_in[0];
    const float* hidden = (const float*)d_in[1];
    const float* enc    = (const float*)d_in[2];
    const float* W1_w   = (const float*)d_in[3];
    const float* W1_b   = (const float*)d_in[4];
    const float* W2_w   = (const float*)d_in[5];
    const float* W2_b   = (const float*)d_in[6];
    const float* V_w    = (const float*)d_in[7];
    // d_in[8] = V_b: constant over the softmax axis -> no effect on attn; skipped.
    const float* emb    = (const float*)d_in[9];
    const float* l1_W   = (const float*)d_in[10]; const float* l1_b = (const float*)d_in[11];
    const float* l2_W   = (const float*)d_in[12]; const float* l2_b = (const float*)d_in[13];
    const float* l3_W   = (const float*)d_in[14]; const float* l3_b = (const float*)d_in[15];
    const float* l4_W   = (const float*)d_in[16]; const float* l4_b = (const float*)d_in[17];
    const float* fc_w   = (const float*)d_in[18]; const float* fc_b = (const float*)d_in[19];
    float* out = (float*)d_out;

    char* p = (char*)d_ws;
    auto alloc = [&](size_t bytes) { char* r = p; p += (bytes + 255) & ~(size_t)255; return r; };
    uint16_t* W1t      = (uint16_t*)alloc(1024u * 1024 * 2);
    uint16_t* W2t      = (uint16_t*)alloc(1024u * 1024 * 2);
    uint16_t* l1t      = (uint16_t*)alloc(4096u * 1280 * 2);
    uint16_t* l2t      = (uint16_t*)alloc(4096u * 2048 * 2);
    uint16_t* l3t      = (uint16_t*)alloc(4096u * 2048 * 2);
    uint16_t* l4t      = (uint16_t*)alloc(4096u * 2048 * 2);
    uint16_t* fct      = (uint16_t*)alloc(32000u * 1024 * 2);
    uint16_t* hidden16 = (uint16_t*)alloc(128u * 1024 * 2);
    uint16_t* inp1_16  = (uint16_t*)alloc(128u * 1280 * 2);
    uint16_t* inpL16   = (uint16_t*)alloc(128u * 2048 * 2);
    uint16_t* h16      = (uint16_t*)alloc(128u * 1024 * 2);
    float*    q        = (float*)alloc(128u * 1024 * 4);
    float*    score    = (float*)alloc(32768u * 4);
    float*    z        = (float*)alloc(128u * 4096 * 4);

    // weight prep
    cvt_bf16<<<64, 256, 0, stream>>>(hidden, hidden16, 131072 / 8);
    transpose_cvt<<<32 * 16, 256, 0, stream>>>(W1_w, W1t, 1024, 1024);
    transpose_cvt<<<32 * 16, 256, 0, stream>>>(W2_w, W2t, 1024, 1024);
    transpose_cvt<<<40 * 64, 256, 0, stream>>>(l1_W, l1t, 1280, 4096);
    transpose_cvt<<<64 * 64, 256, 0, stream>>>(l2_W, l2t, 2048, 4096);
    transpose_cvt<<<64 * 64, 256, 0, stream>>>(l3_W, l3t, 2048, 4096);
    transpose_cvt<<<64 * 64, 256, 0, stream>>>(l4_W, l4t, 2048, 4096);
    transpose_cvt<<<32 * 500, 256, 0, stream>>>(fc_w, fct, 1024, 32000);
    hipMemsetAsync(score, 0, 32768 * sizeof(float), stream);

    // attention
    gemm_skinny<<<64, 256, 0, stream>>>(hidden16, W1t, W1_b, q, 1024, 1024);
    gemm_big<<<2048, 256, 0, stream>>>(enc, W2t, q, W2_b, V_w, score);
    softmax_S<<<128, 256, 0, stream>>>(score);
    embed_k<<<128, 256, 0, stream>>>(x, emb, inp1_16);
    context_k<<<512, 256, 0, stream>>>(score, enc, inp1_16, inpL16);

    // LSTM stack
    gemm_skinny<<<256, 256, 0, stream>>>(inp1_16, l1t, l1_b, z, 4096, 1280);
    gates_k<<<512, 256, 0, stream>>>(z, inpL16, nullptr, nullptr);
    gemm_skinny<<<256, 256, 0, stream>>>(inpL16, l2t, l2_b, z, 4096, 2048);
    gates_k<<<512, 256, 0, stream>>>(z, inpL16, nullptr, nullptr);
    gemm_skinny<<<256, 256, 0, stream>>>(inpL16, l3t, l3_b, z, 4096, 2048);
    gates_k<<<512, 256, 0, stream>>>(z, inpL16, nullptr, nullptr);
    gemm_skinny<<<256, 256, 0, stream>>>(inpL16, l4t, l4_b, z, 4096, 2048);
    gates_k<<<512, 256, 0, stream>>>(z, inpL16, out + 4096000, h16);

    // vocab projection
    gemm_skinny<<<2000, 256, 0, stream>>>(h16, fct, fc_b, out, 32000, 1024);
}